// Round 6
// baseline (135.524 us; speedup 1.0000x reference)
//
#include <hip/hip_runtime.h>
#include <math.h>

#define N 4096
#define D 768
#define MARGIN 1.0f
#define NBLK 528   // 32*33/2 upper-triangular 128x128 tiles

typedef _Float16 half8 __attribute__((ext_vector_type(8)));
typedef _Float16 half4 __attribute__((ext_vector_type(4)));
typedef float f32x4 __attribute__((ext_vector_type(4)));

__device__ __forceinline__ void gl2lds16(const void* g, void* l) {
    __builtin_amdgcn_global_load_lds((const __attribute__((address_space(1))) void*)g,
                                     (__attribute__((address_space(3))) void*)l, 16, 0, 0);
}

// ---------------- Kernel 1: row L2-normalize (wave-per-row) + init ----------
__global__ __launch_bounds__(256) void normalize_kernel(const float* __restrict__ x,
                                                        _Float16* __restrict__ e,
                                                        float* __restrict__ sq,
                                                        unsigned* __restrict__ ap_bits,
                                                        unsigned* __restrict__ an_bits,
                                                        unsigned* __restrict__ counter) {
    const int tid = threadIdx.x;
    const int wave = tid >> 6, lane = tid & 63;
    const int row = blockIdx.x * 4 + wave;

    const float4* xr = (const float4*)(x + (size_t)row * D);   // 192 float4/row
    float4 f0 = xr[lane];
    float4 f1 = xr[lane + 64];
    float4 f2 = xr[lane + 128];

    float s = f0.x*f0.x + f0.y*f0.y + f0.z*f0.z + f0.w*f0.w
            + f1.x*f1.x + f1.y*f1.y + f1.z*f1.z + f1.w*f1.w
            + f2.x*f2.x + f2.y*f2.y + f2.z*f2.z + f2.w*f2.w;
    #pragma unroll
    for (int off = 1; off < 64; off <<= 1) s += __shfl_xor(s, off, 64);

    float scale = 1.0f / fmaxf(sqrtf(s), 1e-12f);

    half4* er = (half4*)(e + (size_t)row * D);
    half4 h0 = { (_Float16)(f0.x*scale), (_Float16)(f0.y*scale), (_Float16)(f0.z*scale), (_Float16)(f0.w*scale) };
    half4 h1 = { (_Float16)(f1.x*scale), (_Float16)(f1.y*scale), (_Float16)(f1.z*scale), (_Float16)(f1.w*scale) };
    half4 h2 = { (_Float16)(f2.x*scale), (_Float16)(f2.y*scale), (_Float16)(f2.z*scale), (_Float16)(f2.w*scale) };
    er[lane]       = h0;
    er[lane + 64]  = h1;
    er[lane + 128] = h2;

    if (lane == 0) {
        sq[row] = s * scale * scale;
        ap_bits[row] = 0u;                 // float 0.0  (max init)
        an_bits[row] = 0x7f800000u;        // +inf       (min init)
    }
    if (blockIdx.x == 0 && tid == 0) *counter = 0u;
}

// ------- Kernel 2: MFMA Gram + mining (triangular, static dbuf) + finalize ---
__global__ __launch_bounds__(256) void mine_kernel(const _Float16* __restrict__ e,
                                                   const float* __restrict__ sq,
                                                   const int* __restrict__ labels,
                                                   unsigned* __restrict__ ap_bits,
                                                   unsigned* __restrict__ an_bits,
                                                   unsigned* __restrict__ counter,
                                                   float* __restrict__ out) {
    __shared__ unsigned short S[16384];  // two 16 KB buffers: [A 8KB | B 8KB] x 2

    // XCD-aware swizzle: blocks land round-robin on 8 XCDs; give each XCD a
    // contiguous band of 66 triangular tiles so A-tile rows stay hot in its L2.
    const int b = blockIdx.x;
    const int t = (b & 7) * 66 + (b >> 3);

    int bi = 0, rem = t;
    while (rem >= 32 - bi) { rem -= 32 - bi; ++bi; }
    const int bj = bi + rem;
    const int i0 = bi * 128, j0 = bj * 128;
    const bool diag = (bi == bj);

    const int tid  = threadIdx.x;
    const int w    = tid >> 6;
    const int lane = tid & 63;
    const int wi   = (w & 1) * 64;       // wave's row quadrant
    const int wj   = (w >> 1) * 64;      // wave's col quadrant
    const int ln15 = lane & 15;
    const int lq   = lane >> 4;          // 0..3

    f32x4 acc[4][4] = {};

    // stage K-tile k0 into buffer at byte offset bufB (0 or 16384)
    auto stage = [&](int k0, int bufB) {
        #pragma unroll
        for (int p = 0; p < 2; ++p) {
            int s  = p * 256 + tid;
            int r  = s >> 2;
            int kg = (s & 3) ^ ((r >> 1) & 3);      // XOR swizzle
            gl2lds16(e + (size_t)(i0 + r) * D + k0 + kg * 8,
                     (char*)S + bufB + (p * 256 + w * 64) * 16);
        }
        #pragma unroll
        for (int p = 0; p < 2; ++p) {
            int s  = p * 256 + tid;
            int r  = s >> 2;
            int kg = (s & 3) ^ ((r >> 1) & 3);
            gl2lds16(e + (size_t)(j0 + r) * D + k0 + kg * 8,
                     (char*)S + bufB + 8192 + (p * 256 + w * 64) * 16);
        }
    };
    // consume buffer at ushort offset bufU (0 or 8192)
    auto compute = [&](int bufU) {
        half8 af[4], bf[4];
        #pragma unroll
        for (int mt = 0; mt < 4; ++mt) {
            int r  = wi + mt * 16 + ln15;
            int kx = lq ^ ((r >> 1) & 3);
            af[mt] = *(const half8*)&S[bufU + r * 32 + kx * 8];
        }
        #pragma unroll
        for (int nt = 0; nt < 4; ++nt) {
            int r  = wj + nt * 16 + ln15;
            int kx = lq ^ ((r >> 1) & 3);
            bf[nt] = *(const half8*)&S[bufU + 4096 + r * 32 + kx * 8];
        }
        #pragma unroll
        for (int mt = 0; mt < 4; ++mt)
            #pragma unroll
            for (int nt = 0; nt < 4; ++nt)
                acc[mt][nt] = __builtin_amdgcn_mfma_f32_16x16x32_f16(af[mt], bf[nt], acc[mt][nt], 0, 0, 0);
    };

    stage(0, 0);
    #pragma unroll 1
    for (int kt = 0; kt < 24; kt += 2) {
        __syncthreads();                               // buf0 ready
        if (kt + 1 < 24) stage((kt + 1) * 32, 16384);  // prefetch overlaps compute
        compute(0);
        __syncthreads();                               // buf1 ready; buf0 readers done
        if (kt + 2 < 24) stage((kt + 2) * 32, 0);
        compute(8192);
    }

    // ---------------- epilogue: dist + dual-sided batch-hard mining ----------
    float sqi[4][4]; int labi[4][4];
    #pragma unroll
    for (int mt = 0; mt < 4; ++mt)
        #pragma unroll
        for (int rg = 0; rg < 4; ++rg) {
            int i = i0 + wi + mt * 16 + lq * 4 + rg;
            sqi[mt][rg] = sq[i];
            labi[mt][rg] = labels[i];
        }
    float sqj[4]; int labj[4];
    #pragma unroll
    for (int nt = 0; nt < 4; ++nt) {
        int j = j0 + wj + nt * 16 + ln15;
        sqj[nt] = sq[j];
        labj[nt] = labels[j];
    }

    float api[4][4], ani[4][4], apj[4], anj[4];
    #pragma unroll
    for (int mt = 0; mt < 4; ++mt)
        #pragma unroll
        for (int rg = 0; rg < 4; ++rg) { api[mt][rg] = -INFINITY; ani[mt][rg] = INFINITY; }
    #pragma unroll
    for (int nt = 0; nt < 4; ++nt) { apj[nt] = -INFINITY; anj[nt] = INFINITY; }

    #pragma unroll
    for (int nt = 0; nt < 4; ++nt) {
        int j = j0 + wj + nt * 16 + ln15;
        #pragma unroll
        for (int mt = 0; mt < 4; ++mt)
            #pragma unroll
            for (int rg = 0; rg < 4; ++rg) {
                int i = i0 + wi + mt * 16 + lq * 4 + rg;
                float d2 = sqi[mt][rg] + sqj[nt] - 2.0f * acc[mt][nt][rg];
                float dist = sqrtf(fmaxf(d2, 0.0f) + 1e-12f);
                if (labi[mt][rg] == labj[nt]) {
                    if (i != j) {
                        api[mt][rg] = fmaxf(api[mt][rg], dist);
                        apj[nt]     = fmaxf(apj[nt], dist);
                    }
                } else {
                    ani[mt][rg] = fminf(ani[mt][rg], dist);
                    anj[nt]     = fminf(anj[nt], dist);
                }
            }
    }

    // i-side reduce over the 16 ln15-lanes
    #pragma unroll
    for (int mt = 0; mt < 4; ++mt)
        #pragma unroll
        for (int rg = 0; rg < 4; ++rg) {
            float a_ = api[mt][rg], n_ = ani[mt][rg];
            #pragma unroll
            for (int off = 1; off < 16; off <<= 1) {
                a_ = fmaxf(a_, __shfl_xor(a_, off, 64));
                n_ = fminf(n_, __shfl_xor(n_, off, 64));
            }
            if (ln15 == 0) {
                int i = i0 + wi + mt * 16 + lq * 4 + rg;
                if (a_ > -1.0e37f) atomicMax(&ap_bits[i], __float_as_uint(a_));
                if (n_ <  1.0e37f) atomicMin(&an_bits[i], __float_as_uint(n_));
            }
        }

    // j-side reduce over the 4 lq-quads (off-diagonal only)
    if (!diag) {
        #pragma unroll
        for (int nt = 0; nt < 4; ++nt) {
            float a_ = apj[nt], n_ = anj[nt];
            #pragma unroll
            for (int off = 16; off < 64; off <<= 1) {
                a_ = fmaxf(a_, __shfl_xor(a_, off, 64));
                n_ = fminf(n_, __shfl_xor(n_, off, 64));
            }
            if (lq == 0) {
                int j = j0 + wj + nt * 16 + ln15;
                if (a_ > -1.0e37f) atomicMax(&ap_bits[j], __float_as_uint(a_));
                if (n_ <  1.0e37f) atomicMin(&an_bits[j], __float_as_uint(n_));
            }
        }
    }

    // ---- last-block finalize: NO fences. Mining writes are device-scope
    // atomics (coherent at L2 coherence point); __syncthreads drains them
    // (vmcnt 0) before the counter bump; last block reads them back with
    // device-scope atomic loads.
    __shared__ unsigned lastFlag;
    __syncthreads();
    if (tid == 0) lastFlag = (atomicAdd(counter, 1u) == NBLK - 1) ? 1u : 0u;
    __syncthreads();
    if (!lastFlag) return;

    __shared__ int cnt[4];
    __shared__ float red[8];
    if (tid < 4) cnt[tid] = 0;
    __syncthreads();
    int local[4] = {0, 0, 0, 0};
    for (int i = tid; i < N; i += 256) local[labels[i] & 3]++;
    #pragma unroll
    for (int c = 0; c < 4; c++) atomicAdd(&cnt[c], local[c]);
    __syncthreads();

    float sum = 0.f, nv = 0.f;
    for (int i = tid; i < N; i += 256) {
        int l = labels[i] & 3;
        if (cnt[l] >= 2) {
            nv += 1.f;
            float apv = __uint_as_float(atomicAdd(&ap_bits[i], 0u));  // coherent read
            float anv = __uint_as_float(atomicAdd(&an_bits[i], 0u));
            if (anv < 3.0e38f) sum += fmaxf(apv - anv + MARGIN, 0.f);
        }
    }

    #pragma unroll
    for (int off = 32; off; off >>= 1) {
        sum += __shfl_down(sum, off, 64);
        nv  += __shfl_down(nv,  off, 64);
    }
    if ((tid & 63) == 0) { red[tid >> 6] = sum; red[4 + (tid >> 6)] = nv; }
    __syncthreads();
    if (tid == 0) {
        float s = red[0] + red[1] + red[2] + red[3];
        float n = red[4] + red[5] + red[6] + red[7];
        out[0] = s / fmaxf(n, 1.f);
    }
}

// ---------------- Launch ----------------
extern "C" void kernel_launch(void* const* d_in, const int* in_sizes, int n_in,
                              void* d_out, int out_size, void* d_ws, size_t ws_size,
                              hipStream_t stream) {
    const float* x = (const float*)d_in[0];
    const int* labels = (const int*)d_in[1];
    float* out = (float*)d_out;

    _Float16* e = (_Float16*)d_ws;
    float* sq = (float*)(e + (size_t)N * D);
    unsigned* ap_bits = (unsigned*)(sq + N);
    unsigned* an_bits = ap_bits + N;
    unsigned* counter = an_bits + N;

    normalize_kernel<<<N / 4, 256, 0, stream>>>(x, e, sq, ap_bits, an_bits, counter);
    mine_kernel<<<NBLK, 256, 0, stream>>>(e, sq, labels, ap_bits, an_bits, counter, out);
}